// Round 3
// baseline (447.041 us; speedup 1.0000x reference)
//
#include <hip/hip_runtime.h>
#include <stdint.h>

#define L_SEQ 2048
#define NB 2
#define EMB 2048
#define II 2048
#define NH 16
#define DH 128
#define MROWS (L_SEQ * NB)  // 4096

typedef __attribute__((ext_vector_type(8))) short bf16x8;
typedef __attribute__((ext_vector_type(4))) float f32x4;
typedef unsigned short u16;
typedef unsigned int u32;

__device__ __forceinline__ u16 f2bf(float f) {
  u32 u = __builtin_bit_cast(u32, f);
  u = u + 0x7fffu + ((u >> 16) & 1u);
  return (u16)(u >> 16);
}
__device__ __forceinline__ u16 f2bf_trunc(float f) {
  return (u16)(__builtin_bit_cast(u32, f) >> 16);
}

// async global->LDS, 16B/lane; HW dest = wave-uniform base + lane*16.
__device__ __forceinline__ void gl_lds16(const void* g, const u16* l) {
  __builtin_amdgcn_global_load_lds(
      (const __attribute__((address_space(1))) void*)(uintptr_t)g,
      (__attribute__((address_space(3))) void*)(u32)(uintptr_t)l, 16, 0, 0);
}

// All five f32->bf16 casts in one launch.
__global__ __launch_bounds__(256) void cast_all(
    const float* __restrict__ q, const float* __restrict__ w0, const float* __restrict__ w1,
    const float* __restrict__ w2, const float* __restrict__ w3, u16* __restrict__ dq,
    u16* __restrict__ dw) {
  const int b = blockIdx.x, t = threadIdx.x;
  const float* src;
  u16* dst;
  int idx;
  if (b < 8192) {
    src = q; dst = dq; idx = b * 256 + t;
  } else {
    int u = b - 8192;
    int sel = u >> 12;
    src = (sel == 0) ? w0 : (sel == 1) ? w1 : (sel == 2) ? w2 : w3;
    dst = dw + (size_t)sel * II * EMB;
    idx = (u & 4095) * 256 + t;
  }
  float4 v = ((const float4*)src)[idx];
  ushort4 o;
  o.x = f2bf(v.x); o.y = f2bf(v.y); o.z = f2bf(v.z); o.w = f2bf(v.w);
  ((ushort4*)dst)[idx] = o;
}

// V [head][L][DH] -> Vt [head][DH][L], 64-l x 128-d tiles.
__global__ __launch_bounds__(256) void transpose_v(const u16* __restrict__ V,
                                                   u16* __restrict__ Vt) {
  __shared__ u16 tile[128][72];
  const int lb = blockIdx.x * 64;
  const int h = blockIdx.y;
  const u16* src = V + (size_t)h * L_SEQ * DH;
  u16* dst = Vt + (size_t)h * DH * L_SEQ;
  const int t = threadIdx.x;
  {
    const int l = t & 63, d0 = (t >> 6) * 32;
#pragma unroll
    for (int c = 0; c < 4; c++) {
      uint4 u = *(const uint4*)(src + (size_t)(lb + l) * DH + d0 + c * 8);
      const u16* e = (const u16*)&u;
#pragma unroll
      for (int x = 0; x < 8; x++) tile[d0 + c * 8 + x][l] = e[x];
    }
  }
  __syncthreads();
  {
    const int d = t >> 1, lc = (t & 1) * 32;
#pragma unroll
    for (int c = 0; c < 4; c++) {
      uint4 u = *(const uint4*)&tile[d][lc + c * 8];
      *(uint4*)(dst + (size_t)d * L_SEQ + lb + lc + c * 8) = u;
    }
  }
}

// ---------------------------------------------------------------------------
// QKV GEMM, 256x256 tile, BK=64, 8 waves (2M x 4N, 128x64 per wave),
// 4 phases per K-tile, DEEP staggered pipeline (sub-tile rotation):
//
// LDS per buffer: A units A0..A3 (64 rows each), B units B0..B3.
// Reads: A0/A2 of cur are read ONLY in ph0 (afr reused in ph1); A1/A3 only in
// ph2 (reused ph3); B unit wn4 read in all 4 phases. Hence A0/A2 of cur may be
// overwritten from ph2 onward -> tile T+2's A0/A2 stage into CUR during T.ph2.
//
// Steady state (per-thread, 1 load per stage unit):
//   T.ph0: issue B(T+1) x4            (first read T+1.ph0, 4 phases later)
//   T.ph1: issue A1,A3(T+1); vmcnt(8) (completes A1,A3(T), issued 4 ph ago)
//   T.ph2: issue A0,A2(T+2) into cur  (first read T+2.ph0, 6 phases later)
//   T.ph3: vmcnt(4)                   (completes A0A2(T+1) @5ph, B(T+1) @3ph)
// Invariant entering T.ph0: outstanding = {A1A3(T), A0A2(T+1)} = 4.
// Tail: T==NT-1 -> ph1 wait vmcnt(0), ph3 no wait; T==NT-2 -> ph3 vmcnt(2).
// Min issue->wait distance = 3 phases (~1200cy) > HBM latency (~900cy).
// ---------------------------------------------------------------------------
#define BK8 64
#define NT8 (EMB / BK8)  // 32

__global__ __launch_bounds__(512, 2) void gemm_qkv_8p(
    const u16* __restrict__ A, const u16* __restrict__ B, const float* __restrict__ qb,
    const float* __restrict__ kb, const float* __restrict__ vb, u16* __restrict__ out_bf,
    float qscale) {
  __shared__ __align__(16) u16 sm[2][32768];  // per buf: A [256][64] @0, B [256][64] @16384
  const int t = threadIdx.x;
  const int lane = t & 63, wv = t >> 6;
  const int quad = lane >> 4, l15 = lane & 15, x7 = l15 & 7;
  const int wm2 = wv >> 2, wn4 = wv & 3;
  const int srow = lane >> 3;                   // row-in-8 within a stage unit
  const int schunk = (lane & 7) ^ (lane >> 3);  // inverse-swizzled global 16B chunk

  // 384 blocks = 8 XCDs x 48; chunk along N so 16 consecutive blocks share a
  // B-panel (1 MB, L2-resident per XCD).
  const int bid = blockIdx.x;
  const int swz = (bid & 7) * 48 + (bid >> 3);
  const int bxx = swz >> 4;  // 0..23  N-tile
  const int byy = swz & 15;  // 0..15  M-tile
  const int n0 = bxx * 256, m0 = byy * 256;

  const u16* abase = A + (size_t)m0 * EMB;
  const u16* bbase = B + (size_t)n0 * EMB;

  // buf: 0 -> sm[0], 1 -> sm[1] (avoid LDS-pointer arrays: addrspacecast issue)
  auto stageA = [&](int buf, int k0, int u) {
    int row = u * 64 + wv * 8 + srow;
    const u16* dst = (buf ? sm[1] : sm[0]) + u * 4096 + wv * 512;
    gl_lds16(abase + (size_t)row * EMB + k0 + schunk * 8, dst);
  };
  auto stageB = [&](int buf, int k0, int u) {
    int row = u * 64 + wv * 8 + srow;
    const u16* dst = (buf ? sm[1] : sm[0]) + 16384 + u * 4096 + wv * 512;
    gl_lds16(bbase + (size_t)row * EMB + k0 + schunk * 8, dst);
  };

  // Prologue mirrors steady-state issue order:
  //   A0A2(T0) [(T-2).ph2 slot], B(T0)x4 [(T-1).ph0], A1A3(T0) [(T-1).ph1],
  //   A0A2(T1) [(T-1).ph2]; vmcnt(4) completes A0A2(T0)+B(T0).
  stageA(0, 0, 0); stageA(0, 0, 2);
  stageB(0, 0, 0); stageB(0, 0, 1); stageB(0, 0, 2); stageB(0, 0, 3);
  stageA(0, 0, 1); stageA(0, 0, 3);
  stageA(1, BK8, 0); stageA(1, BK8, 2);
  __asm__ volatile("s_waitcnt vmcnt(4)" ::: "memory");
  __builtin_amdgcn_s_barrier();

  f32x4 acc[8][4] = {};
  bf16x8 afr[4][2];  // A frags live across the (njp=0, njp=1) phase pair

#pragma unroll 1
  for (int tt = 0; tt < NT8; ++tt) {
    const int cb = tt & 1, nb_ = (tt + 1) & 1;
    const u16* cur = cb ? sm[1] : sm[0];
    const int kn1 = (tt + 1) * BK8;
    const int kn2 = (tt + 2) * BK8;
    const bool pf1 = (tt + 1 < NT8);
    const bool pf2 = (tt + 2 < NT8);

    // ---- phase 0: quadrant (mh=0, njp=0); stage B(T+1) x4 ----
    {
#pragma unroll
      for (int mi = 0; mi < 4; mi++)
#pragma unroll
        for (int ks = 0; ks < 2; ks++)
          afr[mi][ks] =
              *(const bf16x8*)(cur + (wm2 * 128 + mi * 16 + l15) * 64 + (((ks * 4 + quad) ^ x7)) * 8);
      bf16x8 bfr2[2][2];
#pragma unroll
      for (int nj = 0; nj < 2; nj++)
#pragma unroll
        for (int ks = 0; ks < 2; ks++)
          bfr2[nj][ks] = *(const bf16x8*)(cur + 16384 + (wn4 * 64 + nj * 16 + l15) * 64 +
                                          (((ks * 4 + quad) ^ x7)) * 8);
      if (pf1) { stageB(nb_, kn1, 0); stageB(nb_, kn1, 1); stageB(nb_, kn1, 2); stageB(nb_, kn1, 3); }
      __builtin_amdgcn_s_barrier();
      __builtin_amdgcn_s_setprio(1);
#pragma unroll
      for (int ks = 0; ks < 2; ks++)
#pragma unroll
        for (int mi = 0; mi < 4; mi++)
#pragma unroll
          for (int nj = 0; nj < 2; nj++)
            acc[mi][nj] =
                __builtin_amdgcn_mfma_f32_16x16x32_bf16(afr[mi][ks], bfr2[nj][ks], acc[mi][nj], 0, 0, 0);
      __builtin_amdgcn_s_setprio(0);
      __builtin_amdgcn_s_barrier();
    }

    // ---- phase 1: (mh=0, njp=1); reuse afr; stage A1,A3(T+1); vmcnt(8) ----
    {
      bf16x8 bfr2[2][2];
#pragma unroll
      for (int nj = 0; nj < 2; nj++)
#pragma unroll
        for (int ks = 0; ks < 2; ks++)
          bfr2[nj][ks] = *(const bf16x8*)(cur + 16384 + (wn4 * 64 + (nj + 2) * 16 + l15) * 64 +
                                          (((ks * 4 + quad) ^ x7)) * 8);
      if (pf1) {
        stageA(nb_, kn1, 1); stageA(nb_, kn1, 3);
        __asm__ volatile("s_waitcnt vmcnt(8)" ::: "memory");
      } else {
        __asm__ volatile("s_waitcnt vmcnt(0)" ::: "memory");
      }
      __builtin_amdgcn_s_barrier();
      __builtin_amdgcn_s_setprio(1);
#pragma unroll
      for (int ks = 0; ks < 2; ks++)
#pragma unroll
        for (int mi = 0; mi < 4; mi++)
#pragma unroll
          for (int nj = 0; nj < 2; nj++)
            acc[mi][nj + 2] =
                __builtin_amdgcn_mfma_f32_16x16x32_bf16(afr[mi][ks], bfr2[nj][ks], acc[mi][nj + 2], 0, 0, 0);
      __builtin_amdgcn_s_setprio(0);
      __builtin_amdgcn_s_barrier();
    }

    // ---- phase 2: (mh=1, njp=0); stage A0,A2(T+2) into CUR (A0/A2 free) ----
    {
#pragma unroll
      for (int mi = 0; mi < 4; mi++)
#pragma unroll
        for (int ks = 0; ks < 2; ks++)
          afr[mi][ks] = *(const bf16x8*)(cur + (wm2 * 128 + (mi + 4) * 16 + l15) * 64 +
                                         (((ks * 4 + quad) ^ x7)) * 8);
      bf16x8 bfr2[2][2];
#pragma unroll
      for (int nj = 0; nj < 2; nj++)
#pragma unroll
        for (int ks = 0; ks < 2; ks++)
          bfr2[nj][ks] = *(const bf16x8*)(cur + 16384 + (wn4 * 64 + nj * 16 + l15) * 64 +
                                          (((ks * 4 + quad) ^ x7)) * 8);
      if (pf2) { stageA(cb, kn2, 0); stageA(cb, kn2, 2); }
      __builtin_amdgcn_s_barrier();
      __builtin_amdgcn_s_setprio(1);
#pragma unroll
      for (int ks = 0; ks < 2; ks++)
#pragma unroll
        for (int mi = 0; mi < 4; mi++)
#pragma unroll
          for (int nj = 0; nj < 2; nj++)
            acc[mi + 4][nj] =
                __builtin_amdgcn_mfma_f32_16x16x32_bf16(afr[mi][ks], bfr2[nj][ks], acc[mi + 4][nj], 0, 0, 0);
      __builtin_amdgcn_s_setprio(0);
      __builtin_amdgcn_s_barrier();
    }

    // ---- phase 3: (mh=1, njp=1); reuse afr; vmcnt(4)/(2) ----
    {
      bf16x8 bfr2[2][2];
#pragma unroll
      for (int nj = 0; nj < 2; nj++)
#pragma unroll
        for (int ks = 0; ks < 2; ks++)
          bfr2[nj][ks] = *(const bf16x8*)(cur + 16384 + (wn4 * 64 + (nj + 2) * 16 + l15) * 64 +
                                          (((ks * 4 + quad) ^ x7)) * 8);
      if (pf2) {
        __asm__ volatile("s_waitcnt vmcnt(4)" ::: "memory");
      } else if (pf1) {
        __asm__ volatile("s_waitcnt vmcnt(2)" ::: "memory");
      }
      __builtin_amdgcn_s_barrier();
      __builtin_amdgcn_s_setprio(1);
#pragma unroll
      for (int ks = 0; ks < 2; ks++)
#pragma unroll
        for (int mi = 0; mi < 4; mi++)
#pragma unroll
          for (int nj = 0; nj < 2; nj++)
            acc[mi + 4][nj + 2] =
                __builtin_amdgcn_mfma_f32_16x16x32_bf16(afr[mi][ks], bfr2[nj][ks], acc[mi + 4][nj + 2], 0, 0, 0);
      __builtin_amdgcn_s_setprio(0);
      __builtin_amdgcn_s_barrier();
    }
  }

  // Epilogue: bias + optional qscale, scatter to [mat][head][L][DH] bf16.
  const int mat = n0 >> 11;  // BN=256 divides 2048: block-uniform
  const float* bp = (mat == 0) ? qb : (mat == 1) ? kb : vb;
  const float sc2 = (mat == 0) ? qscale : 1.0f;
#pragma unroll
  for (int mi = 0; mi < 8; mi++) {
#pragma unroll
    for (int nj = 0; nj < 4; nj++) {
#pragma unroll
      for (int r = 0; r < 4; r++) {
        int row = m0 + wm2 * 128 + mi * 16 + quad * 4 + r;
        int col = n0 + wn4 * 64 + nj * 16 + l15;
        int cc = col & 2047;
        float v = (acc[mi][nj][r] + bp[cc]) * sc2;
        int l = row >> 1, nb = row & 1;
        int hh = cc >> 7, dd = cc & 127;
        out_bf[(size_t)mat * MROWS * II + ((size_t)(nb * NH + hh) * L_SEQ + l) * DH + dd] =
            f2bf(v);
      }
    }
  }
}

// C = A(bf16 MxK rm) * B(bf16 NdxK rm)^T + bias. BK=64, XOR-swizzled LDS.
// Retained (verified) 128x128 kernel, used for the out-projection (mode 1).
__global__ __launch_bounds__(256) void gemm_nt(
    const u16* __restrict__ A, const u16* __restrict__ B, const float* __restrict__ b0,
    const float* __restrict__ b1, const float* __restrict__ b2, u16* __restrict__ out_bf,
    float* __restrict__ out_f, int Nd, int K, float qscale, int mode) {
  __shared__ __align__(16) u16 a_sm[128 * 64];
  __shared__ __align__(16) u16 b_sm[128 * 64];
  const int t = threadIdx.x;
  const int lane = t & 63, wv = t >> 6;
  const int quad = lane >> 4, l15 = lane & 15;
  const int x7 = l15 & 7;
  const int wm = (wv >> 1) * 64, wn = (wv & 1) * 64;
  const int m0 = blockIdx.y * 128, n0 = blockIdx.x * 128;
  const int srow = lane >> 3;
  const int schunk = (lane & 7) ^ (lane >> 3);

  f32x4 acc[4][4] = {};
  const u16* abase = A + (size_t)m0 * K;
  const u16* bbase = B + (size_t)n0 * K;

  for (int k0 = 0; k0 < K; k0 += 64) {
    __syncthreads();
#pragma unroll
    for (int j = 0; j < 4; j++) {
      int ci = wv * 4 + j;
      int row = ci * 8 + srow;
      gl_lds16(abase + (size_t)row * K + k0 + schunk * 8, a_sm + ci * 512);
      gl_lds16(bbase + (size_t)row * K + k0 + schunk * 8, b_sm + ci * 512);
    }
    __syncthreads();
#pragma unroll
    for (int ks = 0; ks < 2; ks++) {
      bf16x8 af[4], bfr[4];
#pragma unroll
      for (int i = 0; i < 4; i++)
        af[i] = *(const bf16x8*)(a_sm + (wm + i * 16 + l15) * 64 + ((ks * 4 + quad) ^ x7) * 8);
#pragma unroll
      for (int j = 0; j < 4; j++)
        bfr[j] = *(const bf16x8*)(b_sm + (wn + j * 16 + l15) * 64 + ((ks * 4 + quad) ^ x7) * 8);
#pragma unroll
      for (int i = 0; i < 4; i++)
#pragma unroll
        for (int j = 0; j < 4; j++)
          acc[i][j] = __builtin_amdgcn_mfma_f32_16x16x32_bf16(af[i], bfr[j], acc[i][j], 0, 0, 0);
    }
  }

  const int mat = n0 >> 11;
  const float* bp = (mode == 1) ? b0 : (mat == 0 ? b0 : (mat == 1 ? b1 : b2));
  const float sc2 = (mode == 0 && mat == 0) ? qscale : 1.0f;
#pragma unroll
  for (int i = 0; i < 4; i++) {
#pragma unroll
    for (int j = 0; j < 4; j++) {
#pragma unroll
      for (int r = 0; r < 4; r++) {
        int row = m0 + wm + i * 16 + quad * 4 + r;
        int col = n0 + wn + j * 16 + l15;
        if (mode == 0) {
          int cc = col & 2047;
          float v = (acc[i][j][r] + bp[cc]) * sc2;
          int l = row >> 1, nb = row & 1;
          int hh = cc >> 7, dd = cc & 127;
          out_bf[(size_t)mat * MROWS * II + ((size_t)(nb * NH + hh) * L_SEQ + l) * DH + dd] =
              f2bf(v);
        } else {
          out_f[(size_t)row * Nd + col] = acc[i][j][r] + bp[col];
        }
      }
    }
  }
}

// Causal flash attention v4. Base-2 no-max softmax (qscale folded at projection).
__global__ __launch_bounds__(256, 2) void flash_attn(
    const u16* __restrict__ Qh, const u16* __restrict__ Kh, const u16* __restrict__ Vt,
    u16* __restrict__ ctx) {
  __shared__ __align__(16) u16 k_sm[128 * 128];  // [key][d], chunk-swizzled
  __shared__ __align__(16) u16 v_sm[128 * 128];  // [d][key], chunk-swizzled
  const int bx = blockIdx.x;
  const int nh = ((bx & 7) << 2) | ((bx >> 3) & 3);
  const int g = (bx >> 5) & 7;
  const int qt = (bx < 256) ? (15 - g) : g;
  const int q0 = qt * 128;
  const int nK = qt + 1;
  const int t = threadIdx.x;
  const int lane = t & 63, wv = t >> 6;
  const int quad = lane >> 4, l15 = lane & 15;
  const int x7 = l15 & 7;
  const size_t hq = (size_t)nh * L_SEQ * DH;
  const u16* qp = Qh + hq;
  const u16* kp = Kh + hq;
  const u16* vp = Vt + hq;  // [DH][L]
  const int n = nh >> 4, h = nh & 15;
  const int srow = lane >> 4;
  const int spos = lane & 15;
  u16* pw = k_sm + wv * 4096;

  bf16x8 qf[2][4];
#pragma unroll
  for (int mi = 0; mi < 2; mi++)
#pragma unroll
    for (int ks = 0; ks < 4; ks++)
      qf[mi][ks] = *(const bf16x8*)(qp + (size_t)(q0 + wv * 32 + mi * 16 + l15) * DH +
                                    ks * 32 + quad * 8);

  f32x4 o_acc[2][8] = {};
  float l_part[2][4] = {};

#pragma unroll 1
  for (int jb = 0; jb < nK; jb++) {
    const int kb = jb * 128;
    __syncthreads();
#pragma unroll
    for (int i = 0; i < 8; i++) {
      int ci = wv * 8 + i;
      int row = ci * 4 + srow;
      int gc = spos ^ (row & 7);
      gl_lds16(kp + (size_t)(kb + row) * DH + gc * 8, k_sm + ci * 512);
      gl_lds16(vp + (size_t)row * L_SEQ + kb + gc * 8, v_sm + ci * 512);
    }
    __syncthreads();

    // S = Q K^T
    f32x4 s[2][8] = {};
    __builtin_amdgcn_s_setprio(1);
#pragma unroll
    for (int nt = 0; nt < 8; nt++) {
#pragma unroll
      for (int ks = 0; ks < 4; ks++) {
        bf16x8 kf = *(const bf16x8*)(k_sm + (nt * 16 + l15) * 128 + ((ks * 4 + quad) ^ x7) * 8);
#pragma unroll
        for (int mi = 0; mi < 2; mi++)
          s[mi][nt] = __builtin_amdgcn_mfma_f32_16x16x32_bf16(qf[mi][ks], kf, s[mi][nt], 0, 0, 0);
      }
    }
    __builtin_amdgcn_s_setprio(0);
    __syncthreads();  // all k_sm reads drained before P overwrites it

    const bool diag = (jb == qt);
#pragma unroll
    for (int mi = 0; mi < 2; mi++) {
      const int rowg = q0 + wv * 32 + mi * 16 + quad * 4;
#pragma unroll
      for (int nt = 0; nt < 8; nt++) {
        const int colg = kb + nt * 16 + l15;
#pragma unroll
        for (int r = 0; r < 4; r++) {
          float p = __builtin_amdgcn_exp2f(s[mi][nt][r]);
          if (diag && colg > rowg + r) p = 0.f;
          l_part[mi][r] += p;
          int pr = mi * 16 + quad * 4 + r;
          int chunk = nt * 2 + (l15 >> 3);
          int pos = chunk ^ (pr & 7);
          pw[pr * 128 + pos * 8 + (l15 & 7)] = f2bf_trunc(p);
        }
      }
    }
    __asm__ volatile("s_waitcnt lgkmcnt(0)" ::: "memory");

    // O += P V
    bf16x8 pf[2][4];
#pragma unroll
    for (int mi = 0; mi < 2; mi++)
#pragma unroll
      for (int ks = 0; ks < 4; ks++)
        pf[mi][ks] = *(const bf16x8*)(pw + (mi * 16 + l15) * 128 + ((ks * 4 + quad) ^ x7) * 8);
    __builtin_amdgcn_s_setprio(1);
#pragma unroll
    for (int nt = 0; nt < 8; nt++) {
#pragma unroll
      for (int ks = 0; ks < 4; ks++) {
        bf16x8 vf = *(const bf16x8*)(v_sm + (nt * 16 + l15) * 128 + ((ks * 4 + quad) ^ x7) * 8);
#pragma unroll
        for (int mi = 0; mi < 2; mi++)
          o_acc[mi][nt] =
              __builtin_amdgcn_mfma_f32_16x16x32_bf16(pf[mi][ks], vf, o_acc[mi][nt], 0, 0, 0);
      }
    }
    __builtin_amdgcn_s_setprio(0);
  }

  // Epilogue: reduce denominators across the 16-lane row group, write ctx.
#pragma unroll
  for (int mi = 0; mi < 2; mi++) {
#pragma unroll
    for (int r = 0; r < 4; r++) {
      float lv = l_part[mi][r];
#pragma unroll
      for (int off = 1; off < 16; off <<= 1) lv += __shfl_xor(lv, off, 64);
      float inv = 1.f / lv;
      const int lrow = q0 + wv * 32 + mi * 16 + quad * 4 + r;
#pragma unroll
      for (int nt = 0; nt < 8; nt++) {
        int dd = nt * 16 + l15;
        ctx[((size_t)lrow * NB + n) * EMB + h * DH + dd] = f2bf(o_acc[mi][nt][r] * inv);
      }
    }
  }
}

extern "C" void kernel_launch(void* const* d_in, const int* in_sizes, int n_in,
                              void* d_out, int out_size, void* d_ws, size_t ws_size,
                              hipStream_t stream) {
  const float* query    = (const float*)d_in[0];
  const float* q_proj   = (const float*)d_in[1];
  const float* q_bias   = (const float*)d_in[2];
  const float* k_proj   = (const float*)d_in[3];
  const float* k_bias   = (const float*)d_in[4];
  const float* v_proj   = (const float*)d_in[5];
  const float* v_bias   = (const float*)d_in[6];
  const float* out_proj = (const float*)d_in[7];
  const float* out_bias = (const float*)d_in[8];

  u16* ws  = (u16*)d_ws;
  u16* Xbf = ws;                                  // 4096x2048 (dead after QKV gemm)
  u16* Wq  = Xbf + (size_t)MROWS * EMB;           // Wq|Wk|Wv contiguous = [6144,2048]
  u16* Wk  = Wq + (size_t)II * EMB;
  u16* Wv  = Wk + (size_t)II * EMB;
  u16* Wo  = Wv + (size_t)II * EMB;
  u16* Qw  = Wo + (size_t)EMB * II;               // [NB*NH][L][DH], Q|K|V contiguous
  u16* Kw  = Qw + (size_t)MROWS * II;
  u16* Vw  = Kw + (size_t)MROWS * II;
  u16* Cw  = Vw + (size_t)MROWS * II;             // ctx [L][NB][EMB]
  u16* Vtb = Xbf;                                 // Vt [NB*NH][DH][L] aliases Xbf

  cast_all<<<8192 + 4 * 4096, 256, 0, stream>>>(query, q_proj, k_proj, v_proj, out_proj,
                                                Xbf, Wq);

  // d^-0.5 * log2(e): base-2 softmax
  const float qscale = 0.08838834764831845f * 1.4426950408889634f;
  gemm_qkv_8p<<<384, 512, 0, stream>>>(Xbf, Wq, q_bias, k_bias, v_bias, Qw, qscale);

  transpose_v<<<dim3(L_SEQ / 64, NB * NH), 256, 0, stream>>>(Vw, Vtb);

  flash_attn<<<512, 256, 0, stream>>>(Qw, Kw, Vtb, Cw);

  gemm_nt<<<dim3(EMB / 128, MROWS / 128), 256, 0, stream>>>(
      Cw, Wo, out_bias, nullptr, nullptr, nullptr, (float*)d_out, EMB, II, 1.0f, 1);
}

// Round 4
// 400.636 us; speedup vs baseline: 1.1158x; 1.1158x over previous
//
#include <hip/hip_runtime.h>
#include <stdint.h>

#define L_SEQ 2048
#define NB 2
#define EMB 2048
#define II 2048
#define NH 16
#define DH 128
#define MROWS (L_SEQ * NB)  // 4096

typedef __attribute__((ext_vector_type(8))) short bf16x8;
typedef __attribute__((ext_vector_type(4))) float f32x4;
typedef unsigned short u16;
typedef unsigned int u32;

__device__ __forceinline__ u16 f2bf(float f) {
  u32 u = __builtin_bit_cast(u32, f);
  u = u + 0x7fffu + ((u >> 16) & 1u);
  return (u16)(u >> 16);
}
__device__ __forceinline__ u16 f2bf_trunc(float f) {
  return (u16)(__builtin_bit_cast(u32, f) >> 16);
}

// async global->LDS, 16B/lane; HW dest = wave-uniform base + lane*16.
__device__ __forceinline__ void gl_lds16(const void* g, const u16* l) {
  __builtin_amdgcn_global_load_lds(
      (const __attribute__((address_space(1))) void*)(uintptr_t)g,
      (__attribute__((address_space(3))) void*)(u32)(uintptr_t)l, 16, 0, 0);
}

// All five f32->bf16 casts in one launch.
__global__ __launch_bounds__(256) void cast_all(
    const float* __restrict__ q, const float* __restrict__ w0, const float* __restrict__ w1,
    const float* __restrict__ w2, const float* __restrict__ w3, u16* __restrict__ dq,
    u16* __restrict__ dw) {
  const int b = blockIdx.x, t = threadIdx.x;
  const float* src;
  u16* dst;
  int idx;
  if (b < 8192) {
    src = q; dst = dq; idx = b * 256 + t;
  } else {
    int u = b - 8192;
    int sel = u >> 12;
    src = (sel == 0) ? w0 : (sel == 1) ? w1 : (sel == 2) ? w2 : w3;
    dst = dw + (size_t)sel * II * EMB;
    idx = (u & 4095) * 256 + t;
  }
  float4 v = ((const float4*)src)[idx];
  ushort4 o;
  o.x = f2bf(v.x); o.y = f2bf(v.y); o.z = f2bf(v.z); o.w = f2bf(v.w);
  ((ushort4*)dst)[idx] = o;
}

// V [head][L][DH] -> Vt [head][DH][L], 64-l x 128-d tiles.
__global__ __launch_bounds__(256) void transpose_v(const u16* __restrict__ V,
                                                   u16* __restrict__ Vt) {
  __shared__ u16 tile[128][72];
  const int lb = blockIdx.x * 64;
  const int h = blockIdx.y;
  const u16* src = V + (size_t)h * L_SEQ * DH;
  u16* dst = Vt + (size_t)h * DH * L_SEQ;
  const int t = threadIdx.x;
  {
    const int l = t & 63, d0 = (t >> 6) * 32;
#pragma unroll
    for (int c = 0; c < 4; c++) {
      uint4 u = *(const uint4*)(src + (size_t)(lb + l) * DH + d0 + c * 8);
      const u16* e = (const u16*)&u;
#pragma unroll
      for (int x = 0; x < 8; x++) tile[d0 + c * 8 + x][l] = e[x];
    }
  }
  __syncthreads();
  {
    const int d = t >> 1, lc = (t & 1) * 32;
#pragma unroll
    for (int c = 0; c < 4; c++) {
      uint4 u = *(const uint4*)&tile[d][lc + c * 8];
      *(uint4*)(dst + (size_t)d * L_SEQ + lb + lc + c * 8) = u;
    }
  }
}

// ---------------------------------------------------------------------------
// QKV GEMM, 256x256 tile, BK=64, 8 waves (2M x 4N, 128x64 per wave),
// 4 phases per K-tile, deep staggered pipeline (kept from R3: 143 us).
// ---------------------------------------------------------------------------
#define BK8 64
#define NT8 (EMB / BK8)  // 32

__global__ __launch_bounds__(512, 2) void gemm_qkv_8p(
    const u16* __restrict__ A, const u16* __restrict__ B, const float* __restrict__ qb,
    const float* __restrict__ kb, const float* __restrict__ vb, u16* __restrict__ out_bf,
    float qscale) {
  __shared__ __align__(16) u16 sm[2][32768];  // per buf: A [256][64] @0, B [256][64] @16384
  const int t = threadIdx.x;
  const int lane = t & 63, wv = t >> 6;
  const int quad = lane >> 4, l15 = lane & 15, x7 = l15 & 7;
  const int wm2 = wv >> 2, wn4 = wv & 3;
  const int srow = lane >> 3;                   // row-in-8 within a stage unit
  const int schunk = (lane & 7) ^ (lane >> 3);  // inverse-swizzled global 16B chunk

  const int bid = blockIdx.x;
  const int swz = (bid & 7) * 48 + (bid >> 3);
  const int bxx = swz >> 4;  // 0..23  N-tile
  const int byy = swz & 15;  // 0..15  M-tile
  const int n0 = bxx * 256, m0 = byy * 256;

  const u16* abase = A + (size_t)m0 * EMB;
  const u16* bbase = B + (size_t)n0 * EMB;

  auto stageA = [&](int buf, int k0, int u) {
    int row = u * 64 + wv * 8 + srow;
    const u16* dst = (buf ? sm[1] : sm[0]) + u * 4096 + wv * 512;
    gl_lds16(abase + (size_t)row * EMB + k0 + schunk * 8, dst);
  };
  auto stageB = [&](int buf, int k0, int u) {
    int row = u * 64 + wv * 8 + srow;
    const u16* dst = (buf ? sm[1] : sm[0]) + 16384 + u * 4096 + wv * 512;
    gl_lds16(bbase + (size_t)row * EMB + k0 + schunk * 8, dst);
  };

  stageA(0, 0, 0); stageA(0, 0, 2);
  stageB(0, 0, 0); stageB(0, 0, 1); stageB(0, 0, 2); stageB(0, 0, 3);
  stageA(0, 0, 1); stageA(0, 0, 3);
  stageA(1, BK8, 0); stageA(1, BK8, 2);
  __asm__ volatile("s_waitcnt vmcnt(4)" ::: "memory");
  __builtin_amdgcn_s_barrier();

  f32x4 acc[8][4] = {};
  bf16x8 afr[4][2];

#pragma unroll 1
  for (int tt = 0; tt < NT8; ++tt) {
    const int cb = tt & 1, nb_ = (tt + 1) & 1;
    const u16* cur = cb ? sm[1] : sm[0];
    const int kn1 = (tt + 1) * BK8;
    const int kn2 = (tt + 2) * BK8;
    const bool pf1 = (tt + 1 < NT8);
    const bool pf2 = (tt + 2 < NT8);

    // ---- phase 0: (mh=0, njp=0); stage B(T+1) x4 ----
    {
#pragma unroll
      for (int mi = 0; mi < 4; mi++)
#pragma unroll
        for (int ks = 0; ks < 2; ks++)
          afr[mi][ks] =
              *(const bf16x8*)(cur + (wm2 * 128 + mi * 16 + l15) * 64 + (((ks * 4 + quad) ^ x7)) * 8);
      bf16x8 bfr2[2][2];
#pragma unroll
      for (int nj = 0; nj < 2; nj++)
#pragma unroll
        for (int ks = 0; ks < 2; ks++)
          bfr2[nj][ks] = *(const bf16x8*)(cur + 16384 + (wn4 * 64 + nj * 16 + l15) * 64 +
                                          (((ks * 4 + quad) ^ x7)) * 8);
      if (pf1) { stageB(nb_, kn1, 0); stageB(nb_, kn1, 1); stageB(nb_, kn1, 2); stageB(nb_, kn1, 3); }
      __builtin_amdgcn_s_barrier();
      __builtin_amdgcn_s_setprio(1);
#pragma unroll
      for (int ks = 0; ks < 2; ks++)
#pragma unroll
        for (int mi = 0; mi < 4; mi++)
#pragma unroll
          for (int nj = 0; nj < 2; nj++)
            acc[mi][nj] =
                __builtin_amdgcn_mfma_f32_16x16x32_bf16(afr[mi][ks], bfr2[nj][ks], acc[mi][nj], 0, 0, 0);
      __builtin_amdgcn_s_setprio(0);
      __builtin_amdgcn_s_barrier();
    }

    // ---- phase 1: (mh=0, njp=1); reuse afr; stage A1,A3(T+1); vmcnt(8) ----
    {
      bf16x8 bfr2[2][2];
#pragma unroll
      for (int nj = 0; nj < 2; nj++)
#pragma unroll
        for (int ks = 0; ks < 2; ks++)
          bfr2[nj][ks] = *(const bf16x8*)(cur + 16384 + (wn4 * 64 + (nj + 2) * 16 + l15) * 64 +
                                          (((ks * 4 + quad) ^ x7)) * 8);
      if (pf1) {
        stageA(nb_, kn1, 1); stageA(nb_, kn1, 3);
        __asm__ volatile("s_waitcnt vmcnt(8)" ::: "memory");
      } else {
        __asm__ volatile("s_waitcnt vmcnt(0)" ::: "memory");
      }
      __builtin_amdgcn_s_barrier();
      __builtin_amdgcn_s_setprio(1);
#pragma unroll
      for (int ks = 0; ks < 2; ks++)
#pragma unroll
        for (int mi = 0; mi < 4; mi++)
#pragma unroll
          for (int nj = 0; nj < 2; nj++)
            acc[mi][nj + 2] =
                __builtin_amdgcn_mfma_f32_16x16x32_bf16(afr[mi][ks], bfr2[nj][ks], acc[mi][nj + 2], 0, 0, 0);
      __builtin_amdgcn_s_setprio(0);
      __builtin_amdgcn_s_barrier();
    }

    // ---- phase 2: (mh=1, njp=0); stage A0,A2(T+2) into CUR ----
    {
#pragma unroll
      for (int mi = 0; mi < 4; mi++)
#pragma unroll
        for (int ks = 0; ks < 2; ks++)
          afr[mi][ks] = *(const bf16x8*)(cur + (wm2 * 128 + (mi + 4) * 16 + l15) * 64 +
                                         (((ks * 4 + quad) ^ x7)) * 8);
      bf16x8 bfr2[2][2];
#pragma unroll
      for (int nj = 0; nj < 2; nj++)
#pragma unroll
        for (int ks = 0; ks < 2; ks++)
          bfr2[nj][ks] = *(const bf16x8*)(cur + 16384 + (wn4 * 64 + nj * 16 + l15) * 64 +
                                          (((ks * 4 + quad) ^ x7)) * 8);
      if (pf2) { stageA(cb, kn2, 0); stageA(cb, kn2, 2); }
      __builtin_amdgcn_s_barrier();
      __builtin_amdgcn_s_setprio(1);
#pragma unroll
      for (int ks = 0; ks < 2; ks++)
#pragma unroll
        for (int mi = 0; mi < 4; mi++)
#pragma unroll
          for (int nj = 0; nj < 2; nj++)
            acc[mi + 4][nj] =
                __builtin_amdgcn_mfma_f32_16x16x32_bf16(afr[mi][ks], bfr2[nj][ks], acc[mi + 4][nj], 0, 0, 0);
      __builtin_amdgcn_s_setprio(0);
      __builtin_amdgcn_s_barrier();
    }

    // ---- phase 3: (mh=1, njp=1); reuse afr; vmcnt(4)/(2) ----
    {
      bf16x8 bfr2[2][2];
#pragma unroll
      for (int nj = 0; nj < 2; nj++)
#pragma unroll
        for (int ks = 0; ks < 2; ks++)
          bfr2[nj][ks] = *(const bf16x8*)(cur + 16384 + (wn4 * 64 + (nj + 2) * 16 + l15) * 64 +
                                          (((ks * 4 + quad) ^ x7)) * 8);
      if (pf2) {
        __asm__ volatile("s_waitcnt vmcnt(4)" ::: "memory");
      } else if (pf1) {
        __asm__ volatile("s_waitcnt vmcnt(2)" ::: "memory");
      }
      __builtin_amdgcn_s_barrier();
      __builtin_amdgcn_s_setprio(1);
#pragma unroll
      for (int ks = 0; ks < 2; ks++)
#pragma unroll
        for (int mi = 0; mi < 4; mi++)
#pragma unroll
          for (int nj = 0; nj < 2; nj++)
            acc[mi + 4][nj + 2] =
                __builtin_amdgcn_mfma_f32_16x16x32_bf16(afr[mi][ks], bfr2[nj][ks], acc[mi + 4][nj + 2], 0, 0, 0);
      __builtin_amdgcn_s_setprio(0);
      __builtin_amdgcn_s_barrier();
    }
  }

  const int mat = n0 >> 11;
  const float* bp = (mat == 0) ? qb : (mat == 1) ? kb : vb;
  const float sc2 = (mat == 0) ? qscale : 1.0f;
#pragma unroll
  for (int mi = 0; mi < 8; mi++) {
#pragma unroll
    for (int nj = 0; nj < 4; nj++) {
#pragma unroll
      for (int r = 0; r < 4; r++) {
        int row = m0 + wm2 * 128 + mi * 16 + quad * 4 + r;
        int col = n0 + wn4 * 64 + nj * 16 + l15;
        int cc = col & 2047;
        float v = (acc[mi][nj][r] + bp[cc]) * sc2;
        int l = row >> 1, nb = row & 1;
        int hh = cc >> 7, dd = cc & 127;
        out_bf[(size_t)mat * MROWS * II + ((size_t)(nb * NH + hh) * L_SEQ + l) * DH + dd] =
            f2bf(v);
      }
    }
  }
}

// C = A(bf16 MxK rm) * B(bf16 NdxK rm)^T + bias. 128x128, used for out-proj.
__global__ __launch_bounds__(256) void gemm_nt(
    const u16* __restrict__ A, const u16* __restrict__ B, const float* __restrict__ b0,
    const float* __restrict__ b1, const float* __restrict__ b2, u16* __restrict__ out_bf,
    float* __restrict__ out_f, int Nd, int K, float qscale, int mode) {
  __shared__ __align__(16) u16 a_sm[128 * 64];
  __shared__ __align__(16) u16 b_sm[128 * 64];
  const int t = threadIdx.x;
  const int lane = t & 63, wv = t >> 6;
  const int quad = lane >> 4, l15 = lane & 15;
  const int x7 = l15 & 7;
  const int wm = (wv >> 1) * 64, wn = (wv & 1) * 64;
  const int m0 = blockIdx.y * 128, n0 = blockIdx.x * 128;
  const int srow = lane >> 3;
  const int schunk = (lane & 7) ^ (lane >> 3);

  f32x4 acc[4][4] = {};
  const u16* abase = A + (size_t)m0 * K;
  const u16* bbase = B + (size_t)n0 * K;

  for (int k0 = 0; k0 < K; k0 += 64) {
    __syncthreads();
#pragma unroll
    for (int j = 0; j < 4; j++) {
      int ci = wv * 4 + j;
      int row = ci * 8 + srow;
      gl_lds16(abase + (size_t)row * K + k0 + schunk * 8, a_sm + ci * 512);
      gl_lds16(bbase + (size_t)row * K + k0 + schunk * 8, b_sm + ci * 512);
    }
    __syncthreads();
#pragma unroll
    for (int ks = 0; ks < 2; ks++) {
      bf16x8 af[4], bfr[4];
#pragma unroll
      for (int i = 0; i < 4; i++)
        af[i] = *(const bf16x8*)(a_sm + (wm + i * 16 + l15) * 64 + ((ks * 4 + quad) ^ x7) * 8);
#pragma unroll
      for (int j = 0; j < 4; j++)
        bfr[j] = *(const bf16x8*)(b_sm + (wn + j * 16 + l15) * 64 + ((ks * 4 + quad) ^ x7) * 8);
#pragma unroll
      for (int i = 0; i < 4; i++)
#pragma unroll
        for (int j = 0; j < 4; j++)
          acc[i][j] = __builtin_amdgcn_mfma_f32_16x16x32_bf16(af[i], bfr[j], acc[i][j], 0, 0, 0);
    }
  }

  const int mat = n0 >> 11;
  const float* bp = (mode == 1) ? b0 : (mat == 0 ? b0 : (mat == 1 ? b1 : b2));
  const float sc2 = (mode == 0 && mat == 0) ? qscale : 1.0f;
#pragma unroll
  for (int i = 0; i < 4; i++) {
#pragma unroll
    for (int j = 0; j < 4; j++) {
#pragma unroll
      for (int r = 0; r < 4; r++) {
        int row = m0 + wm + i * 16 + quad * 4 + r;
        int col = n0 + wn + j * 16 + l15;
        if (mode == 0) {
          int cc = col & 2047;
          float v = (acc[i][j][r] + bp[cc]) * sc2;
          int l = row >> 1, nb = row & 1;
          int hh = cc >> 7, dd = cc & 127;
          out_bf[(size_t)mat * MROWS * II + ((size_t)(nb * NH + hh) * L_SEQ + l) * DH + dd] =
              f2bf(v);
        } else {
          out_f[(size_t)row * Nd + col] = acc[i][j][r] + bp[col];
        }
      }
    }
  }
}

// ---------------------------------------------------------------------------
// Causal flash attention v5: KVBLK=64, double-buffered K/V (2x16KB each,
// 64KB total -> 2 blocks/CU), staging of tile jb+1 issued at TOP of iter jb so
// it overlaps the whole QK+softmax+PV (~1-2K cyc >> L2 latency). Mid-loop
// barrier is RAW (lgkmcnt(0) only, no vmcnt drain) so staging loads stay in
// flight across it. P overlays k_sm[cur] (staging writes buf^1; P of iter jb
// is consumed before iter jb+1's top __syncthreads, whose arrival precedes the
// stage(jb+2) overwrite of buf cur).
// Per iter: QK 2x4x4=32 MFMA, PV 2x8x2=32 MFMA, 32 exp2, 8 stage loads.
// nK = 2*(qt+1); partner blocks (bx, bx+256) sum to 34 iters.
// ---------------------------------------------------------------------------
__global__ __launch_bounds__(256, 2) void flash_attn(
    const u16* __restrict__ Qh, const u16* __restrict__ Kh, const u16* __restrict__ Vt,
    u16* __restrict__ ctx) {
  __shared__ __align__(16) u16 k_sm[2][64 * 128];  // [buf][key][d], chunk-swizzled
  __shared__ __align__(16) u16 v_sm[2][128 * 64];  // [buf][d][key], chunk-swizzled
  const int bx = blockIdx.x;
  const int nh = ((bx & 7) << 2) | ((bx >> 3) & 3);  // 4 heads per XCD
  const int g = (bx >> 5) & 7;
  const int qt = (bx < 256) ? (15 - g) : g;
  const int q0 = qt * 128;
  const int nK = 2 * (qt + 1);
  const int t = threadIdx.x;
  const int lane = t & 63, wv = t >> 6;
  const int quad = lane >> 4, l15 = lane & 15;
  const int x7 = l15 & 7;
  const size_t hq = (size_t)nh * L_SEQ * DH;
  const u16* qp = Qh + hq;
  const u16* kp = Kh + hq;
  const u16* vp = Vt + hq;  // [DH][L]
  const int n = nh >> 4, h = nh & 15;
  const int srow = lane >> 4;  // K staging: row-in-4 (256B rows)
  const int spos = lane & 15;
  const int vrow = lane >> 3;  // V staging: row-in-8 (128B rows)
  const int vpos = lane & 7;

  // stage K/V tile starting at key kb into buffer bb (8 loads/thread).
  auto stageKV = [&](int bb, int kb) {
#pragma unroll
    for (int i = 0; i < 4; i++) {
      int ci = wv * 4 + i;  // 16 1KB units each for K and V
      int krow = ci * 4 + srow;                    // 0..63
      int gck = spos ^ (krow & 7);                 // 16 chunks/row, XOR low3
      gl_lds16(kp + (size_t)(kb + krow) * DH + gck * 8,
               (bb ? k_sm[1] : k_sm[0]) + ci * 512);
      int drow = ci * 8 + vrow;                    // 0..127
      int gcv = vpos ^ (drow & 7);                 // 8 chunks/row
      gl_lds16(vp + (size_t)drow * L_SEQ + kb + gcv * 8,
               (bb ? v_sm[1] : v_sm[0]) + ci * 512);
    }
  };

  // Q fragments: rows q0 + wv*32 + mi*16 + l15.
  bf16x8 qf[2][4];
#pragma unroll
  for (int mi = 0; mi < 2; mi++)
#pragma unroll
    for (int ks = 0; ks < 4; ks++)
      qf[mi][ks] = *(const bf16x8*)(qp + (size_t)(q0 + wv * 32 + mi * 16 + l15) * DH +
                                    ks * 32 + quad * 8);

  f32x4 o_acc[2][8] = {};
  float l_part[2][4] = {};

  stageKV(0, 0);  // prologue: tile 0 -> buf 0

#pragma unroll 1
  for (int jb = 0; jb < nK; jb++) {
    const int b = jb & 1;
    const u16* kbuf = b ? k_sm[1] : k_sm[0];
    const u16* vbuf = b ? v_sm[1] : v_sm[0];
    u16* pwb = (b ? k_sm[1] : k_sm[0]) + wv * 2048;  // per-wave 4KB P slice
    const int kb = jb * 64;

    __syncthreads();  // drains vmcnt(0): stage(jb), issued last iter, complete
    if (jb + 1 < nK) stageKV(b ^ 1, kb + 64);  // overlaps this whole iteration

    // S = Q K^T  (4 key-subtiles x K=128 contraction)
    f32x4 s[2][4] = {};
    __builtin_amdgcn_s_setprio(1);
#pragma unroll
    for (int nt = 0; nt < 4; nt++) {
#pragma unroll
      for (int ks = 0; ks < 4; ks++) {
        bf16x8 kf = *(const bf16x8*)(kbuf + (nt * 16 + l15) * 128 + ((ks * 4 + quad) ^ x7) * 8);
#pragma unroll
        for (int mi = 0; mi < 2; mi++)
          s[mi][nt] = __builtin_amdgcn_mfma_f32_16x16x32_bf16(qf[mi][ks], kf, s[mi][nt], 0, 0, 0);
      }
    }
    __builtin_amdgcn_s_setprio(0);

    // All k_sm[b] reads done before P overwrites it — raw barrier, NO vmcnt
    // drain (stage loads stay in flight).
    __asm__ volatile("s_waitcnt lgkmcnt(0)" ::: "memory");
    __builtin_amdgcn_sched_barrier(0);
    __builtin_amdgcn_s_barrier();
    __builtin_amdgcn_sched_barrier(0);

    const bool diag = (jb >= nK - 2);
#pragma unroll
    for (int mi = 0; mi < 2; mi++) {
      const int rowg = q0 + wv * 32 + mi * 16 + quad * 4;
#pragma unroll
      for (int nt = 0; nt < 4; nt++) {
        const int colg = kb + nt * 16 + l15;
#pragma unroll
        for (int r = 0; r < 4; r++) {
          float p = __builtin_amdgcn_exp2f(s[mi][nt][r]);
          if (diag && colg > rowg + r) p = 0.f;
          l_part[mi][r] += p;
          int pr = mi * 16 + quad * 4 + r;
          int chunk = nt * 2 + (l15 >> 3);
          int pos = chunk ^ (pr & 7);
          pwb[pr * 64 + pos * 8 + (l15 & 7)] = f2bf_trunc(p);
        }
      }
    }
    __asm__ volatile("s_waitcnt lgkmcnt(0)" ::: "memory");
    __builtin_amdgcn_sched_barrier(0);

    // O += P V  (contract over 64 keys = 2 k-steps)
    bf16x8 pf[2][2];
#pragma unroll
    for (int mi = 0; mi < 2; mi++)
#pragma unroll
      for (int ks = 0; ks < 2; ks++)
        pf[mi][ks] = *(const bf16x8*)(pwb + (mi * 16 + l15) * 64 + ((ks * 4 + quad) ^ x7) * 8);
    __builtin_amdgcn_s_setprio(1);
#pragma unroll
    for (int nt = 0; nt < 8; nt++) {
#pragma unroll
      for (int ks = 0; ks < 2; ks++) {
        bf16x8 vf = *(const bf16x8*)(vbuf + (nt * 16 + l15) * 64 + ((ks * 4 + quad) ^ x7) * 8);
#pragma unroll
        for (int mi = 0; mi < 2; mi++)
          o_acc[mi][nt] =
              __builtin_amdgcn_mfma_f32_16x16x32_bf16(pf[mi][ks], vf, o_acc[mi][nt], 0, 0, 0);
      }
    }
    __builtin_amdgcn_s_setprio(0);
  }

  // Epilogue: reduce denominators across the 16-lane row group, write ctx.
#pragma unroll
  for (int mi = 0; mi < 2; mi++) {
#pragma unroll
    for (int r = 0; r < 4; r++) {
      float lv = l_part[mi][r];
#pragma unroll
      for (int off = 1; off < 16; off <<= 1) lv += __shfl_xor(lv, off, 64);
      float inv = 1.f / lv;
      const int lrow = q0 + wv * 32 + mi * 16 + quad * 4 + r;
#pragma unroll
      for (int nt = 0; nt < 8; nt++) {
        int dd = nt * 16 + l15;
        ctx[((size_t)lrow * NB + n) * EMB + h * DH + dd] = f2bf(o_acc[mi][nt][r] * inv);
      }
    }
  }
}

extern "C" void kernel_launch(void* const* d_in, const int* in_sizes, int n_in,
                              void* d_out, int out_size, void* d_ws, size_t ws_size,
                              hipStream_t stream) {
  const float* query    = (const float*)d_in[0];
  const float* q_proj   = (const float*)d_in[1];
  const float* q_bias   = (const float*)d_in[2];
  const float* k_proj   = (const float*)d_in[3];
  const float* k_bias   = (const float*)d_in[4];
  const float* v_proj   = (const float*)d_in[5];
  const float* v_bias   = (const float*)d_in[6];
  const float* out_proj = (const float*)d_in[7];
  const float* out_bias = (const float*)d_in[8];

  u16* ws  = (u16*)d_ws;
  u16* Xbf = ws;                                  // 4096x2048 (dead after QKV gemm)
  u16* Wq  = Xbf + (size_t)MROWS * EMB;           // Wq|Wk|Wv contiguous = [6144,2048]
  u16* Wk  = Wq + (size_t)II * EMB;
  u16* Wv  = Wk + (size_t)II * EMB;
  u16* Wo  = Wv + (size_t)II * EMB;
  u16* Qw  = Wo + (size_t)EMB * II;               // [NB*NH][L][DH], Q|K|V contiguous
  u16* Kw  = Qw + (size_t)MROWS * II;
  u16* Vw  = Kw + (size_t)MROWS * II;
  u16* Cw  = Vw + (size_t)MROWS * II;             // ctx [L][NB][EMB]
  u16* Vtb = Xbf;                                 // Vt [NB*NH][DH][L] aliases Xbf

  cast_all<<<8192 + 4 * 4096, 256, 0, stream>>>(query, q_proj, k_proj, v_proj, out_proj,
                                                Xbf, Wq);

  // d^-0.5 * log2(e): base-2 softmax
  const float qscale = 0.08838834764831845f * 1.4426950408889634f;
  gemm_qkv_8p<<<384, 512, 0, stream>>>(Xbf, Wq, q_bias, k_bias, v_bias, Qw, qscale);

  transpose_v<<<dim3(L_SEQ / 64, NB * NH), 256, 0, stream>>>(Vw, Vtb);

  flash_attn<<<512, 256, 0, stream>>>(Qw, Kw, Vtb, Cw);

  gemm_nt<<<dim3(EMB / 128, MROWS / 128), 256, 0, stream>>>(
      Cw, Wo, out_bias, nullptr, nullptr, nullptr, (float*)d_out, EMB, II, 1.0f, 1);
}

// Round 5
// 369.878 us; speedup vs baseline: 1.2086x; 1.0832x over previous
//
#include <hip/hip_runtime.h>
#include <stdint.h>

#define L_SEQ 2048
#define NB 2
#define EMB 2048
#define II 2048
#define NH 16
#define DH 128
#define MROWS (L_SEQ * NB)  // 4096

typedef __attribute__((ext_vector_type(8))) short bf16x8;
typedef __attribute__((ext_vector_type(4))) float f32x4;
typedef unsigned short u16;
typedef unsigned int u32;

__device__ __forceinline__ u16 f2bf(float f) {
  u32 u = __builtin_bit_cast(u32, f);
  u = u + 0x7fffu + ((u >> 16) & 1u);
  return (u16)(u >> 16);
}
__device__ __forceinline__ u16 f2bf_trunc(float f) {
  return (u16)(__builtin_bit_cast(u32, f) >> 16);
}

// async global->LDS, 16B/lane; HW dest = wave-uniform base + lane*16.
__device__ __forceinline__ void gl_lds16(const void* g, const u16* l) {
  __builtin_amdgcn_global_load_lds(
      (const __attribute__((address_space(1))) void*)(uintptr_t)g,
      (__attribute__((address_space(3))) void*)(u32)(uintptr_t)l, 16, 0, 0);
}

// All five f32->bf16 casts in one launch.
__global__ __launch_bounds__(256) void cast_all(
    const float* __restrict__ q, const float* __restrict__ w0, const float* __restrict__ w1,
    const float* __restrict__ w2, const float* __restrict__ w3, u16* __restrict__ dq,
    u16* __restrict__ dw) {
  const int b = blockIdx.x, t = threadIdx.x;
  const float* src;
  u16* dst;
  int idx;
  if (b < 8192) {
    src = q; dst = dq; idx = b * 256 + t;
  } else {
    int u = b - 8192;
    int sel = u >> 12;
    src = (sel == 0) ? w0 : (sel == 1) ? w1 : (sel == 2) ? w2 : w3;
    dst = dw + (size_t)sel * II * EMB;
    idx = (u & 4095) * 256 + t;
  }
  float4 v = ((const float4*)src)[idx];
  ushort4 o;
  o.x = f2bf(v.x); o.y = f2bf(v.y); o.z = f2bf(v.z); o.w = f2bf(v.w);
  ((ushort4*)dst)[idx] = o;
}

// V [head][L][DH] -> Vt [head][DH][L], 64-l x 128-d tiles.
__global__ __launch_bounds__(256) void transpose_v(const u16* __restrict__ V,
                                                   u16* __restrict__ Vt) {
  __shared__ u16 tile[128][72];
  const int lb = blockIdx.x * 64;
  const int h = blockIdx.y;
  const u16* src = V + (size_t)h * L_SEQ * DH;
  u16* dst = Vt + (size_t)h * DH * L_SEQ;
  const int t = threadIdx.x;
  {
    const int l = t & 63, d0 = (t >> 6) * 32;
#pragma unroll
    for (int c = 0; c < 4; c++) {
      uint4 u = *(const uint4*)(src + (size_t)(lb + l) * DH + d0 + c * 8);
      const u16* e = (const u16*)&u;
#pragma unroll
      for (int x = 0; x < 8; x++) tile[d0 + c * 8 + x][l] = e[x];
    }
  }
  __syncthreads();
  {
    const int d = t >> 1, lc = (t & 1) * 32;
#pragma unroll
    for (int c = 0; c < 4; c++) {
      uint4 u = *(const uint4*)&tile[d][lc + c * 8];
      *(uint4*)(dst + (size_t)d * L_SEQ + lb + lc + c * 8) = u;
    }
  }
}

// ---------------------------------------------------------------------------
// Unified GEMM: 128x256 tile, BK=64, 8 waves (2M x 4N, 64x64 per wave),
// 2 phases per K-tile, deep pipeline (A 2-buf, B 3-buf).
// C = A(4096xK rm) * B(NdxK rm)^T + bias.
//   mode 0 (QKV, Nd=6144, grid 768 = 3.0 rounds): scatter to Q|K|V heads bf16.
//   mode 1 (out,  Nd=2048, grid 256 = 1.0 round): out_f[row*2048+col].
//
// Per-thread ledger (steady state, kk2 = (T+2)*64):
//   T.ph0: ds_read afr(8)+bfr01(4); stage B(T+2) x4 -> b_sm[(tB+2)%3];
//          barrier; 16 MFMA acc[mi][0..1]; barrier.
//   T.ph1: ds_read bfr23(4); stage A(T+2) x2 -> a_sm[T&1] (A(T) region free
//          after ph0's closing barrier); vmcnt(6) — leaves exactly
//          {B(T+2):4, A(T+2):2}; barrier; 16 MFMA acc[mi][2..3]; barrier.
// Distances: B issue->wait 3 phases (~1200cy > HBM 900cy); A 2 phases
// (A is L3-resident, ~450cy). Tail: T=NT-2 -> vmcnt(0); T=NT-1 -> no wait.
// LDS = 2*16KB (A) + 3*32KB (B) = 128 KB -> 1 block/CU.
// ---------------------------------------------------------------------------
#define BK2 64
#define NT2 (EMB / BK2)  // 32

__global__ __launch_bounds__(512, 2) void gemm_2p(
    const u16* __restrict__ A, const u16* __restrict__ B, const float* __restrict__ b0,
    const float* __restrict__ b1, const float* __restrict__ b2, u16* __restrict__ out_bf,
    float* __restrict__ out_f, float qscale, int mode) {
  __shared__ __align__(16) u16 a_sm[2][8192];   // [buf][128 rows][64], chunk-swizzled
  __shared__ __align__(16) u16 b_sm[3][16384];  // [buf][256 rows][64], chunk-swizzled
  const int t = threadIdx.x;
  const int lane = t & 63, wv = t >> 6;
  const int quad = lane >> 4, l15 = lane & 15, x7 = l15 & 7;
  const int wm2 = wv >> 2, wn4 = wv & 3;        // wave tile 64x64 at (wm2*64, wn4*64)
  const int srow = lane >> 3;                   // row-in-8 within a 1KB stage unit
  const int schunk = (lane & 7) ^ (lane >> 3);  // inverse-swizzled global 16B chunk

  // XCD swizzle: 32 consecutive swz share one N-tile (1MB B panel, L2-resident).
  const int bid = blockIdx.x;
  const int cpx = gridDim.x >> 3;  // grid % 8 == 0 (768 or 256)
  const int swz = (bid & 7) * cpx + (bid >> 3);
  const int byy = swz & 31;        // 32 M-tiles (M=4096, BM=128)
  const int bxx = swz >> 5;        // N-tiles
  const int m0 = byy * 128, n0 = bxx * 256;

  const u16* abase = A + (size_t)m0 * EMB;
  const u16* bbase = B + (size_t)n0 * EMB;

  auto stageA = [&](int buf, int k0, int u) {  // u in 0..1 (64 rows each)
    int row = u * 64 + wv * 8 + srow;
    const u16* dst = (buf ? a_sm[1] : a_sm[0]) + u * 4096 + wv * 512;
    gl_lds16(abase + (size_t)row * EMB + k0 + schunk * 8, dst);
  };
  auto stageB = [&](int buf, int k0, int u) {  // u in 0..3, buf in 0..2
    int row = u * 64 + wv * 8 + srow;
    const u16* dst = (buf == 0 ? b_sm[0] : buf == 1 ? b_sm[1] : b_sm[2]) + u * 4096 + wv * 512;
    gl_lds16(bbase + (size_t)row * EMB + k0 + schunk * 8, dst);
  };

  // Prologue: tiles 0 and 1 fully staged, drained.
  stageB(0, 0, 0); stageB(0, 0, 1); stageB(0, 0, 2); stageB(0, 0, 3);
  stageA(0, 0, 0); stageA(0, 0, 1);
  stageB(1, BK2, 0); stageB(1, BK2, 1); stageB(1, BK2, 2); stageB(1, BK2, 3);
  stageA(1, BK2, 0); stageA(1, BK2, 1);
  __asm__ volatile("s_waitcnt vmcnt(0)" ::: "memory");
  __builtin_amdgcn_s_barrier();

  f32x4 acc[4][4] = {};
  int tB = 0;  // B buffer holding tile tt

#pragma unroll 1
  for (int tt = 0; tt < NT2; ++tt) {
    const u16* aC = (tt & 1) ? a_sm[1] : a_sm[0];
    const u16* bC = (tB == 0) ? b_sm[0] : (tB == 1) ? b_sm[1] : b_sm[2];
    const int tB2 = (tB + 2 >= 3) ? tB - 1 : tB + 2;  // (tB+2)%3
    const int kk2 = (tt + 2) * BK2;
    const bool pf2 = (tt + 2 < NT2);

    bf16x8 afr[4][2];  // A frags live across both phases

    // ---- phase 0: nj 0..1; stage B(T+2) x4 ----
    {
#pragma unroll
      for (int mi = 0; mi < 4; mi++)
#pragma unroll
        for (int ks = 0; ks < 2; ks++)
          afr[mi][ks] = *(const bf16x8*)(aC + wm2 * 4096 + (mi * 16 + l15) * 64 +
                                         ((ks * 4 + quad) ^ x7) * 8);
      bf16x8 bfr[2][2];
#pragma unroll
      for (int nj = 0; nj < 2; nj++)
#pragma unroll
        for (int ks = 0; ks < 2; ks++)
          bfr[nj][ks] = *(const bf16x8*)(bC + wn4 * 4096 + (nj * 16 + l15) * 64 +
                                         ((ks * 4 + quad) ^ x7) * 8);
      if (pf2) { stageB(tB2, kk2, 0); stageB(tB2, kk2, 1); stageB(tB2, kk2, 2); stageB(tB2, kk2, 3); }
      __builtin_amdgcn_s_barrier();
      __builtin_amdgcn_s_setprio(1);
#pragma unroll
      for (int ks = 0; ks < 2; ks++)
#pragma unroll
        for (int mi = 0; mi < 4; mi++)
#pragma unroll
          for (int nj = 0; nj < 2; nj++)
            acc[mi][nj] =
                __builtin_amdgcn_mfma_f32_16x16x32_bf16(afr[mi][ks], bfr[nj][ks], acc[mi][nj], 0, 0, 0);
      __builtin_amdgcn_s_setprio(0);
      __builtin_amdgcn_s_barrier();
    }

    // ---- phase 1: nj 2..3; stage A(T+2) x2 into a_sm[tt&1]; vmcnt(6) ----
    {
      bf16x8 bfr[2][2];
#pragma unroll
      for (int nj = 0; nj < 2; nj++)
#pragma unroll
        for (int ks = 0; ks < 2; ks++)
          bfr[nj][ks] = *(const bf16x8*)(bC + wn4 * 4096 + ((nj + 2) * 16 + l15) * 64 +
                                         ((ks * 4 + quad) ^ x7) * 8);
      if (pf2) {
        stageA(tt & 1, kk2, 0); stageA(tt & 1, kk2, 1);
        __asm__ volatile("s_waitcnt vmcnt(6)" ::: "memory");
      } else if (tt == NT2 - 2) {
        __asm__ volatile("s_waitcnt vmcnt(0)" ::: "memory");
      }
      __builtin_amdgcn_s_barrier();
      __builtin_amdgcn_s_setprio(1);
#pragma unroll
      for (int ks = 0; ks < 2; ks++)
#pragma unroll
        for (int mi = 0; mi < 4; mi++)
#pragma unroll
          for (int nj = 0; nj < 2; nj++)
            acc[mi][nj + 2] =
                __builtin_amdgcn_mfma_f32_16x16x32_bf16(afr[mi][ks], bfr[nj][ks], acc[mi][nj + 2], 0, 0, 0);
      __builtin_amdgcn_s_setprio(0);
      __builtin_amdgcn_s_barrier();
    }

    tB = (tB + 1 == 3) ? 0 : tB + 1;
  }

  // Epilogue.
  if (mode == 0) {
    const int mat = n0 >> 11;  // BN=256 divides 2048: block-uniform
    const float* bp = (mat == 0) ? b0 : (mat == 1) ? b1 : b2;
    const float sc2 = (mat == 0) ? qscale : 1.0f;
#pragma unroll
    for (int mi = 0; mi < 4; mi++) {
#pragma unroll
      for (int nj = 0; nj < 4; nj++) {
#pragma unroll
        for (int r = 0; r < 4; r++) {
          int row = m0 + wm2 * 64 + mi * 16 + quad * 4 + r;
          int col = n0 + wn4 * 64 + nj * 16 + l15;
          int cc = col & 2047;
          float v = (acc[mi][nj][r] + bp[cc]) * sc2;
          int l = row >> 1, nb = row & 1;
          int hh = cc >> 7, dd = cc & 127;
          out_bf[(size_t)mat * MROWS * II + ((size_t)(nb * NH + hh) * L_SEQ + l) * DH + dd] =
              f2bf(v);
        }
      }
    }
  } else {
#pragma unroll
    for (int mi = 0; mi < 4; mi++) {
#pragma unroll
      for (int nj = 0; nj < 4; nj++) {
#pragma unroll
        for (int r = 0; r < 4; r++) {
          int row = m0 + wm2 * 64 + mi * 16 + quad * 4 + r;
          int col = n0 + wn4 * 64 + nj * 16 + l15;
          out_f[(size_t)row * EMB + col] = acc[mi][nj][r] + b0[col];
        }
      }
    }
  }
}

// ---------------------------------------------------------------------------
// Causal flash attention v5 (kept from R4: 210 -> ~140 us). KVBLK=64,
// double-buffered K/V, staging of jb+1 issued at top of iter jb (overlaps the
// whole QK+softmax+PV); mid-loop barrier is raw (no vmcnt drain).
// ---------------------------------------------------------------------------
__global__ __launch_bounds__(256, 2) void flash_attn(
    const u16* __restrict__ Qh, const u16* __restrict__ Kh, const u16* __restrict__ Vt,
    u16* __restrict__ ctx) {
  __shared__ __align__(16) u16 k_sm[2][64 * 128];  // [buf][key][d], chunk-swizzled
  __shared__ __align__(16) u16 v_sm[2][128 * 64];  // [buf][d][key], chunk-swizzled
  const int bx = blockIdx.x;
  const int nh = ((bx & 7) << 2) | ((bx >> 3) & 3);  // 4 heads per XCD
  const int g = (bx >> 5) & 7;
  const int qt = (bx < 256) ? (15 - g) : g;
  const int q0 = qt * 128;
  const int nK = 2 * (qt + 1);
  const int t = threadIdx.x;
  const int lane = t & 63, wv = t >> 6;
  const int quad = lane >> 4, l15 = lane & 15;
  const int x7 = l15 & 7;
  const size_t hq = (size_t)nh * L_SEQ * DH;
  const u16* qp = Qh + hq;
  const u16* kp = Kh + hq;
  const u16* vp = Vt + hq;  // [DH][L]
  const int n = nh >> 4, h = nh & 15;
  const int srow = lane >> 4;  // K staging: row-in-4 (256B rows)
  const int spos = lane & 15;
  const int vrow = lane >> 3;  // V staging: row-in-8 (128B rows)
  const int vpos = lane & 7;

  auto stageKV = [&](int bb, int kb) {
#pragma unroll
    for (int i = 0; i < 4; i++) {
      int ci = wv * 4 + i;  // 16 1KB units each for K and V
      int krow = ci * 4 + srow;                    // 0..63
      int gck = spos ^ (krow & 7);
      gl_lds16(kp + (size_t)(kb + krow) * DH + gck * 8,
               (bb ? k_sm[1] : k_sm[0]) + ci * 512);
      int drow = ci * 8 + vrow;                    // 0..127
      int gcv = vpos ^ (drow & 7);
      gl_lds16(vp + (size_t)drow * L_SEQ + kb + gcv * 8,
               (bb ? v_sm[1] : v_sm[0]) + ci * 512);
    }
  };

  bf16x8 qf[2][4];
#pragma unroll
  for (int mi = 0; mi < 2; mi++)
#pragma unroll
    for (int ks = 0; ks < 4; ks++)
      qf[mi][ks] = *(const bf16x8*)(qp + (size_t)(q0 + wv * 32 + mi * 16 + l15) * DH +
                                    ks * 32 + quad * 8);

  f32x4 o_acc[2][8] = {};
  float l_part[2][4] = {};

  stageKV(0, 0);  // prologue: tile 0 -> buf 0

#pragma unroll 1
  for (int jb = 0; jb < nK; jb++) {
    const int b = jb & 1;
    const u16* kbuf = b ? k_sm[1] : k_sm[0];
    const u16* vbuf = b ? v_sm[1] : v_sm[0];
    u16* pwb = (b ? k_sm[1] : k_sm[0]) + wv * 2048;  // per-wave 4KB P slice
    const int kb = jb * 64;

    __syncthreads();  // drains vmcnt(0): stage(jb), issued last iter, complete
    if (jb + 1 < nK) stageKV(b ^ 1, kb + 64);  // overlaps this whole iteration

    // S = Q K^T
    f32x4 s[2][4] = {};
    __builtin_amdgcn_s_setprio(1);
#pragma unroll
    for (int nt = 0; nt < 4; nt++) {
#pragma unroll
      for (int ks = 0; ks < 4; ks++) {
        bf16x8 kf = *(const bf16x8*)(kbuf + (nt * 16 + l15) * 128 + ((ks * 4 + quad) ^ x7) * 8);
#pragma unroll
        for (int mi = 0; mi < 2; mi++)
          s[mi][nt] = __builtin_amdgcn_mfma_f32_16x16x32_bf16(qf[mi][ks], kf, s[mi][nt], 0, 0, 0);
      }
    }
    __builtin_amdgcn_s_setprio(0);

    __asm__ volatile("s_waitcnt lgkmcnt(0)" ::: "memory");
    __builtin_amdgcn_sched_barrier(0);
    __builtin_amdgcn_s_barrier();
    __builtin_amdgcn_sched_barrier(0);

    const bool diag = (jb >= nK - 2);
#pragma unroll
    for (int mi = 0; mi < 2; mi++) {
      const int rowg = q0 + wv * 32 + mi * 16 + quad * 4;
#pragma unroll
      for (int nt = 0; nt < 4; nt++) {
        const int colg = kb + nt * 16 + l15;
#pragma unroll
        for (int r = 0; r < 4; r++) {
          float p = __builtin_amdgcn_exp2f(s[mi][nt][r]);
          if (diag && colg > rowg + r) p = 0.f;
          l_part[mi][r] += p;
          int pr = mi * 16 + quad * 4 + r;
          int chunk = nt * 2 + (l15 >> 3);
          int pos = chunk ^ (pr & 7);
          pwb[pr * 64 + pos * 8 + (l15 & 7)] = f2bf_trunc(p);
        }
      }
    }
    __asm__ volatile("s_waitcnt lgkmcnt(0)" ::: "memory");
    __builtin_amdgcn_sched_barrier(0);

    // O += P V
    bf16x8 pf[2][2];
#pragma unroll
    for (int mi = 0; mi < 2; mi++)
#pragma unroll
      for (int ks = 0; ks < 2; ks++)
        pf[mi][ks] = *(const bf16x8*)(pwb + (mi * 16 + l15) * 64 + ((ks * 4 + quad) ^ x7) * 8);
    __builtin_amdgcn_s_setprio(1);
#pragma unroll
    for (int nt = 0; nt < 8; nt++) {
#pragma unroll
      for (int ks = 0; ks < 2; ks++) {
        bf16x8 vf = *(const bf16x8*)(vbuf + (nt * 16 + l15) * 64 + ((ks * 4 + quad) ^ x7) * 8);
#pragma unroll
        for (int mi = 0; mi < 2; mi++)
          o_acc[mi][nt] =
              __builtin_amdgcn_mfma_f32_16x16x32_bf16(pf[mi][ks], vf, o_acc[mi][nt], 0, 0, 0);
      }
    }
    __builtin_amdgcn_s_setprio(0);
  }

  // Epilogue: reduce denominators across the 16-lane row group, write ctx.
#pragma unroll
  for (int mi = 0; mi < 2; mi++) {
#pragma unroll
    for (int r = 0; r < 4; r++) {
      float lv = l_part[mi][r];
#pragma unroll
      for (int off = 1; off < 16; off <<= 1) lv += __shfl_xor(lv, off, 64);
      float inv = 1.f / lv;
      const int lrow = q0 + wv * 32 + mi * 16 + quad * 4 + r;
#pragma unroll
      for (int nt = 0; nt < 8; nt++) {
        int dd = nt * 16 + l15;
        ctx[((size_t)lrow * NB + n) * EMB + h * DH + dd] = f2bf(o_acc[mi][nt][r] * inv);
      }
    }
  }
}

extern "C" void kernel_launch(void* const* d_in, const int* in_sizes, int n_in,
                              void* d_out, int out_size, void* d_ws, size_t ws_size,
                              hipStream_t stream) {
  const float* query    = (const float*)d_in[0];
  const float* q_proj   = (const float*)d_in[1];
  const float* q_bias   = (const float*)d_in[2];
  const float* k_proj   = (const float*)d_in[3];
  const float* k_bias   = (const float*)d_in[4];
  const float* v_proj   = (const float*)d_in[5];
  const float* v_bias   = (const float*)d_in[6];
  const float* out_proj = (const float*)d_in[7];
  const float* out_bias = (const float*)d_in[8];

  u16* ws  = (u16*)d_ws;
  u16* Xbf = ws;                                  // 4096x2048 (dead after QKV gemm)
  u16* Wq  = Xbf + (size_t)MROWS * EMB;           // Wq|Wk|Wv contiguous = [6144,2048]
  u16* Wk  = Wq + (size_t)II * EMB;
  u16* Wv  = Wk + (size_t)II * EMB;
  u16* Wo  = Wv + (size_t)II * EMB;
  u16* Qw  = Wo + (size_t)EMB * II;               // [NB*NH][L][DH], Q|K|V contiguous
  u16* Kw  = Qw + (size_t)MROWS * II;
  u16* Vw  = Kw + (size_t)MROWS * II;
  u16* Cw  = Vw + (size_t)MROWS * II;             // ctx [L][NB][EMB]
  u16* Vtb = Xbf;                                 // Vt [NB*NH][DH][L] aliases Xbf

  cast_all<<<8192 + 4 * 4096, 256, 0, stream>>>(query, q_proj, k_proj, v_proj, out_proj,
                                                Xbf, Wq);

  // d^-0.5 * log2(e): base-2 softmax
  const float qscale = 0.08838834764831845f * 1.4426950408889634f;
  gemm_2p<<<768, 512, 0, stream>>>(Xbf, Wq, q_bias, k_bias, v_bias, Qw, nullptr, qscale, 0);

  transpose_v<<<dim3(L_SEQ / 64, NB * NH), 256, 0, stream>>>(Vw, Vtb);

  flash_attn<<<512, 256, 0, stream>>>(Qw, Kw, Vtb, Cw);

  gemm_2p<<<256, 512, 0, stream>>>(Cw, Wo, out_bias, nullptr, nullptr, nullptr,
                                   (float*)d_out, 1.0f, 1);
}

// Round 6
// 369.838 us; speedup vs baseline: 1.2088x; 1.0001x over previous
//
#include <hip/hip_runtime.h>
#include <stdint.h>

#define L_SEQ 2048
#define NB 2
#define EMB 2048
#define II 2048
#define NH 16
#define DH 128
#define MROWS (L_SEQ * NB)  // 4096

typedef __attribute__((ext_vector_type(8))) short bf16x8;
typedef __attribute__((ext_vector_type(4))) float f32x4;
typedef unsigned short u16;
typedef unsigned int u32;

__device__ __forceinline__ u16 f2bf(float f) {
  u32 u = __builtin_bit_cast(u32, f);
  u = u + 0x7fffu + ((u >> 16) & 1u);
  return (u16)(u >> 16);
}
__device__ __forceinline__ u16 f2bf_trunc(float f) {
  return (u16)(__builtin_bit_cast(u32, f) >> 16);
}

// async global->LDS, 16B/lane; HW dest = wave-uniform base + lane*16.
__device__ __forceinline__ void gl_lds16(const void* g, const u16* l) {
  __builtin_amdgcn_global_load_lds(
      (const __attribute__((address_space(1))) void*)(uintptr_t)g,
      (__attribute__((address_space(3))) void*)(u32)(uintptr_t)l, 16, 0, 0);
}

// All five f32->bf16 casts in one launch.
__global__ __launch_bounds__(256) void cast_all(
    const float* __restrict__ q, const float* __restrict__ w0, const float* __restrict__ w1,
    const float* __restrict__ w2, const float* __restrict__ w3, u16* __restrict__ dq,
    u16* __restrict__ dw) {
  const int b = blockIdx.x, t = threadIdx.x;
  const float* src;
  u16* dst;
  int idx;
  if (b < 8192) {
    src = q; dst = dq; idx = b * 256 + t;
  } else {
    int u = b - 8192;
    int sel = u >> 12;
    src = (sel == 0) ? w0 : (sel == 1) ? w1 : (sel == 2) ? w2 : w3;
    dst = dw + (size_t)sel * II * EMB;
    idx = (u & 4095) * 256 + t;
  }
  float4 v = ((const float4*)src)[idx];
  ushort4 o;
  o.x = f2bf(v.x); o.y = f2bf(v.y); o.z = f2bf(v.z); o.w = f2bf(v.w);
  ((ushort4*)dst)[idx] = o;
}

// V [head][L][DH] -> Vt [head][DH][L], 64-l x 128-d tiles.
__global__ __launch_bounds__(256) void transpose_v(const u16* __restrict__ V,
                                                   u16* __restrict__ Vt) {
  __shared__ u16 tile[128][72];
  const int lb = blockIdx.x * 64;
  const int h = blockIdx.y;
  const u16* src = V + (size_t)h * L_SEQ * DH;
  u16* dst = Vt + (size_t)h * DH * L_SEQ;
  const int t = threadIdx.x;
  {
    const int l = t & 63, d0 = (t >> 6) * 32;
#pragma unroll
    for (int c = 0; c < 4; c++) {
      uint4 u = *(const uint4*)(src + (size_t)(lb + l) * DH + d0 + c * 8);
      const u16* e = (const u16*)&u;
#pragma unroll
      for (int x = 0; x < 8; x++) tile[d0 + c * 8 + x][l] = e[x];
    }
  }
  __syncthreads();
  {
    const int d = t >> 1, lc = (t & 1) * 32;
#pragma unroll
    for (int c = 0; c < 4; c++) {
      uint4 u = *(const uint4*)&tile[d][lc + c * 8];
      *(uint4*)(dst + (size_t)d * L_SEQ + lb + lc + c * 8) = u;
    }
  }
}

// ---------------------------------------------------------------------------
// Unified GEMM: 128x256 tile, BK=64, 8 waves (2M x 4N, 64x64 per wave),
// 2 phases per K-tile, deep pipeline (A 2-buf, B 3-buf). Kept from R5: QKV
// 121 us (3.0 rounds), out-proj ~1.0 round.
// ---------------------------------------------------------------------------
#define BK2 64
#define NT2 (EMB / BK2)  // 32

__global__ __launch_bounds__(512, 2) void gemm_2p(
    const u16* __restrict__ A, const u16* __restrict__ B, const float* __restrict__ b0,
    const float* __restrict__ b1, const float* __restrict__ b2, u16* __restrict__ out_bf,
    float* __restrict__ out_f, float qscale, int mode) {
  __shared__ __align__(16) u16 a_sm[2][8192];   // [buf][128 rows][64], chunk-swizzled
  __shared__ __align__(16) u16 b_sm[3][16384];  // [buf][256 rows][64], chunk-swizzled
  const int t = threadIdx.x;
  const int lane = t & 63, wv = t >> 6;
  const int quad = lane >> 4, l15 = lane & 15, x7 = l15 & 7;
  const int wm2 = wv >> 2, wn4 = wv & 3;        // wave tile 64x64 at (wm2*64, wn4*64)
  const int srow = lane >> 3;                   // row-in-8 within a 1KB stage unit
  const int schunk = (lane & 7) ^ (lane >> 3);  // inverse-swizzled global 16B chunk

  const int bid = blockIdx.x;
  const int cpx = gridDim.x >> 3;  // grid % 8 == 0 (768 or 256)
  const int swz = (bid & 7) * cpx + (bid >> 3);
  const int byy = swz & 31;        // 32 M-tiles (M=4096, BM=128)
  const int bxx = swz >> 5;        // N-tiles
  const int m0 = byy * 128, n0 = bxx * 256;

  const u16* abase = A + (size_t)m0 * EMB;
  const u16* bbase = B + (size_t)n0 * EMB;

  auto stageA = [&](int buf, int k0, int u) {  // u in 0..1 (64 rows each)
    int row = u * 64 + wv * 8 + srow;
    const u16* dst = (buf ? a_sm[1] : a_sm[0]) + u * 4096 + wv * 512;
    gl_lds16(abase + (size_t)row * EMB + k0 + schunk * 8, dst);
  };
  auto stageB = [&](int buf, int k0, int u) {  // u in 0..3, buf in 0..2
    int row = u * 64 + wv * 8 + srow;
    const u16* dst = (buf == 0 ? b_sm[0] : buf == 1 ? b_sm[1] : b_sm[2]) + u * 4096 + wv * 512;
    gl_lds16(bbase + (size_t)row * EMB + k0 + schunk * 8, dst);
  };

  // Prologue: tiles 0 and 1 fully staged, drained.
  stageB(0, 0, 0); stageB(0, 0, 1); stageB(0, 0, 2); stageB(0, 0, 3);
  stageA(0, 0, 0); stageA(0, 0, 1);
  stageB(1, BK2, 0); stageB(1, BK2, 1); stageB(1, BK2, 2); stageB(1, BK2, 3);
  stageA(1, BK2, 0); stageA(1, BK2, 1);
  __asm__ volatile("s_waitcnt vmcnt(0)" ::: "memory");
  __builtin_amdgcn_s_barrier();

  f32x4 acc[4][4] = {};
  int tB = 0;  // B buffer holding tile tt

#pragma unroll 1
  for (int tt = 0; tt < NT2; ++tt) {
    const u16* aC = (tt & 1) ? a_sm[1] : a_sm[0];
    const u16* bC = (tB == 0) ? b_sm[0] : (tB == 1) ? b_sm[1] : b_sm[2];
    const int tB2 = (tB + 2 >= 3) ? tB - 1 : tB + 2;  // (tB+2)%3
    const int kk2 = (tt + 2) * BK2;
    const bool pf2 = (tt + 2 < NT2);

    bf16x8 afr[4][2];  // A frags live across both phases

    // ---- phase 0: nj 0..1; stage B(T+2) x4 ----
    {
#pragma unroll
      for (int mi = 0; mi < 4; mi++)
#pragma unroll
        for (int ks = 0; ks < 2; ks++)
          afr[mi][ks] = *(const bf16x8*)(aC + wm2 * 4096 + (mi * 16 + l15) * 64 +
                                         ((ks * 4 + quad) ^ x7) * 8);
      bf16x8 bfr[2][2];
#pragma unroll
      for (int nj = 0; nj < 2; nj++)
#pragma unroll
        for (int ks = 0; ks < 2; ks++)
          bfr[nj][ks] = *(const bf16x8*)(bC + wn4 * 4096 + (nj * 16 + l15) * 64 +
                                         ((ks * 4 + quad) ^ x7) * 8);
      if (pf2) { stageB(tB2, kk2, 0); stageB(tB2, kk2, 1); stageB(tB2, kk2, 2); stageB(tB2, kk2, 3); }
      __builtin_amdgcn_s_barrier();
      __builtin_amdgcn_s_setprio(1);
#pragma unroll
      for (int ks = 0; ks < 2; ks++)
#pragma unroll
        for (int mi = 0; mi < 4; mi++)
#pragma unroll
          for (int nj = 0; nj < 2; nj++)
            acc[mi][nj] =
                __builtin_amdgcn_mfma_f32_16x16x32_bf16(afr[mi][ks], bfr[nj][ks], acc[mi][nj], 0, 0, 0);
      __builtin_amdgcn_s_setprio(0);
      __builtin_amdgcn_s_barrier();
    }

    // ---- phase 1: nj 2..3; stage A(T+2) x2 into a_sm[tt&1]; vmcnt(6) ----
    {
      bf16x8 bfr[2][2];
#pragma unroll
      for (int nj = 0; nj < 2; nj++)
#pragma unroll
        for (int ks = 0; ks < 2; ks++)
          bfr[nj][ks] = *(const bf16x8*)(bC + wn4 * 4096 + ((nj + 2) * 16 + l15) * 64 +
                                         ((ks * 4 + quad) ^ x7) * 8);
      if (pf2) {
        stageA(tt & 1, kk2, 0); stageA(tt & 1, kk2, 1);
        __asm__ volatile("s_waitcnt vmcnt(6)" ::: "memory");
      } else if (tt == NT2 - 2) {
        __asm__ volatile("s_waitcnt vmcnt(0)" ::: "memory");
      }
      __builtin_amdgcn_s_barrier();
      __builtin_amdgcn_s_setprio(1);
#pragma unroll
      for (int ks = 0; ks < 2; ks++)
#pragma unroll
        for (int mi = 0; mi < 4; mi++)
#pragma unroll
          for (int nj = 0; nj < 2; nj++)
            acc[mi][nj + 2] =
                __builtin_amdgcn_mfma_f32_16x16x32_bf16(afr[mi][ks], bfr[nj][ks], acc[mi][nj + 2], 0, 0, 0);
      __builtin_amdgcn_s_setprio(0);
      __builtin_amdgcn_s_barrier();
    }

    tB = (tB + 1 == 3) ? 0 : tB + 1;
  }

  // Epilogue.
  if (mode == 0) {
    const int mat = n0 >> 11;  // BN=256 divides 2048: block-uniform
    const float* bp = (mat == 0) ? b0 : (mat == 1) ? b1 : b2;
    const float sc2 = (mat == 0) ? qscale : 1.0f;
#pragma unroll
    for (int mi = 0; mi < 4; mi++) {
#pragma unroll
      for (int nj = 0; nj < 4; nj++) {
#pragma unroll
        for (int r = 0; r < 4; r++) {
          int row = m0 + wm2 * 64 + mi * 16 + quad * 4 + r;
          int col = n0 + wn4 * 64 + nj * 16 + l15;
          int cc = col & 2047;
          float v = (acc[mi][nj][r] + bp[cc]) * sc2;
          int l = row >> 1, nb = row & 1;
          int hh = cc >> 7, dd = cc & 127;
          out_bf[(size_t)mat * MROWS * II + ((size_t)(nb * NH + hh) * L_SEQ + l) * DH + dd] =
              f2bf(v);
        }
      }
    }
  } else {
#pragma unroll
    for (int mi = 0; mi < 4; mi++) {
#pragma unroll
      for (int nj = 0; nj < 4; nj++) {
#pragma unroll
        for (int r = 0; r < 4; r++) {
          int row = m0 + wm2 * 64 + mi * 16 + quad * 4 + r;
          int col = n0 + wn4 * 64 + nj * 16 + l15;
          out_f[(size_t)row * EMB + col] = acc[mi][nj][r] + b0[col];
        }
      }
    }
  }
}

// ---------------------------------------------------------------------------
// Causal flash attention v6: KVBLK=64, double-buffered K/V + WAVE-PRIVATE P
// buffer (p_sm, 4x4KB). LDS 80KB -> 2 blocks/CU. ONE block-wide barrier per
// iteration (the top __syncthreads, which also drains stage(jb)); the mid-loop
// s_barrier from v5 is gone — P no longer overlays k_sm, so waves free-run
// through QK->SM->PV and one wave's softmax VALU overlaps another's MFMA.
// Buffer-rotation safety: stage(jb+2) into buf b is issued after iter jb+1's
// top barrier, which all waves reach only after finishing iter jb's reads of
// buf b.
// ---------------------------------------------------------------------------
__global__ __launch_bounds__(256, 2) void flash_attn(
    const u16* __restrict__ Qh, const u16* __restrict__ Kh, const u16* __restrict__ Vt,
    u16* __restrict__ ctx) {
  __shared__ __align__(16) u16 k_sm[2][64 * 128];  // [buf][key][d], chunk-swizzled
  __shared__ __align__(16) u16 v_sm[2][128 * 64];  // [buf][d][key], chunk-swizzled
  __shared__ __align__(16) u16 p_sm[4][32 * 64];   // [wave][qrow][key], chunk-swizzled
  const int bx = blockIdx.x;
  const int nh = ((bx & 7) << 2) | ((bx >> 3) & 3);  // 4 heads per XCD
  const int g = (bx >> 5) & 7;
  const int qt = (bx < 256) ? (15 - g) : g;
  const int q0 = qt * 128;
  const int nK = 2 * (qt + 1);
  const int t = threadIdx.x;
  const int lane = t & 63, wv = t >> 6;
  const int quad = lane >> 4, l15 = lane & 15;
  const int x7 = l15 & 7;
  const size_t hq = (size_t)nh * L_SEQ * DH;
  const u16* qp = Qh + hq;
  const u16* kp = Kh + hq;
  const u16* vp = Vt + hq;  // [DH][L]
  const int n = nh >> 4, h = nh & 15;
  const int srow = lane >> 4;  // K staging: row-in-4 (256B rows)
  const int spos = lane & 15;
  const int vrow = lane >> 3;  // V staging: row-in-8 (128B rows)
  const int vpos = lane & 7;
  u16* pwb = p_sm[wv];  // per-wave 4KB P slice

  auto stageKV = [&](int bb, int kb) {
#pragma unroll
    for (int i = 0; i < 4; i++) {
      int ci = wv * 4 + i;  // 16 1KB units each for K and V
      int krow = ci * 4 + srow;                    // 0..63
      int gck = spos ^ (krow & 7);
      gl_lds16(kp + (size_t)(kb + krow) * DH + gck * 8,
               (bb ? k_sm[1] : k_sm[0]) + ci * 512);
      int drow = ci * 8 + vrow;                    // 0..127
      int gcv = vpos ^ (drow & 7);
      gl_lds16(vp + (size_t)drow * L_SEQ + kb + gcv * 8,
               (bb ? v_sm[1] : v_sm[0]) + ci * 512);
    }
  };

  bf16x8 qf[2][4];
#pragma unroll
  for (int mi = 0; mi < 2; mi++)
#pragma unroll
    for (int ks = 0; ks < 4; ks++)
      qf[mi][ks] = *(const bf16x8*)(qp + (size_t)(q0 + wv * 32 + mi * 16 + l15) * DH +
                                    ks * 32 + quad * 8);

  f32x4 o_acc[2][8] = {};
  float l_part[2][4] = {};

  stageKV(0, 0);  // prologue: tile 0 -> buf 0

#pragma unroll 1
  for (int jb = 0; jb < nK; jb++) {
    const int b = jb & 1;
    const u16* kbuf = b ? k_sm[1] : k_sm[0];
    const u16* vbuf = b ? v_sm[1] : v_sm[0];
    const int kb = jb * 64;

    // Single per-iter block sync: drains vmcnt(0) -> stage(jb) complete, and
    // guarantees all waves finished iter jb-1's reads of buf b^1 before the
    // stage below overwrites it... (stage below writes b^1, read by jb+1).
    __syncthreads();
    if (jb + 1 < nK) stageKV(b ^ 1, kb + 64);  // overlaps this whole iteration

    // S = Q K^T
    f32x4 s[2][4] = {};
    __builtin_amdgcn_s_setprio(1);
#pragma unroll
    for (int nt = 0; nt < 4; nt++) {
#pragma unroll
      for (int ks = 0; ks < 4; ks++) {
        bf16x8 kf = *(const bf16x8*)(kbuf + (nt * 16 + l15) * 128 + ((ks * 4 + quad) ^ x7) * 8);
#pragma unroll
        for (int mi = 0; mi < 2; mi++)
          s[mi][nt] = __builtin_amdgcn_mfma_f32_16x16x32_bf16(qf[mi][ks], kf, s[mi][nt], 0, 0, 0);
      }
    }
    __builtin_amdgcn_s_setprio(0);

    // Softmax -> wave-private P (no block sync needed).
    const bool diag = (jb >= nK - 2);
#pragma unroll
    for (int mi = 0; mi < 2; mi++) {
      const int rowg = q0 + wv * 32 + mi * 16 + quad * 4;
#pragma unroll
      for (int nt = 0; nt < 4; nt++) {
        const int colg = kb + nt * 16 + l15;
#pragma unroll
        for (int r = 0; r < 4; r++) {
          float p = __builtin_amdgcn_exp2f(s[mi][nt][r]);
          if (diag && colg > rowg + r) p = 0.f;
          l_part[mi][r] += p;
          int pr = mi * 16 + quad * 4 + r;
          int chunk = nt * 2 + (l15 >> 3);
          int pos = chunk ^ (pr & 7);
          pwb[pr * 64 + pos * 8 + (l15 & 7)] = f2bf_trunc(p);
        }
      }
    }
    __asm__ volatile("s_waitcnt lgkmcnt(0)" ::: "memory");
    __builtin_amdgcn_sched_barrier(0);

    // O += P V
    bf16x8 pf[2][2];
#pragma unroll
    for (int mi = 0; mi < 2; mi++)
#pragma unroll
      for (int ks = 0; ks < 2; ks++)
        pf[mi][ks] = *(const bf16x8*)(pwb + (mi * 16 + l15) * 64 + ((ks * 4 + quad) ^ x7) * 8);
    __builtin_amdgcn_s_setprio(1);
#pragma unroll
    for (int nt = 0; nt < 8; nt++) {
#pragma unroll
      for (int ks = 0; ks < 2; ks++) {
        bf16x8 vf = *(const bf16x8*)(vbuf + (nt * 16 + l15) * 64 + ((ks * 4 + quad) ^ x7) * 8);
#pragma unroll
        for (int mi = 0; mi < 2; mi++)
          o_acc[mi][nt] =
              __builtin_amdgcn_mfma_f32_16x16x32_bf16(pf[mi][ks], vf, o_acc[mi][nt], 0, 0, 0);
      }
    }
    __builtin_amdgcn_s_setprio(0);
  }

  // Epilogue: reduce denominators across the 16-lane row group, write ctx.
#pragma unroll
  for (int mi = 0; mi < 2; mi++) {
#pragma unroll
    for (int r = 0; r < 4; r++) {
      float lv = l_part[mi][r];
#pragma unroll
      for (int off = 1; off < 16; off <<= 1) lv += __shfl_xor(lv, off, 64);
      float inv = 1.f / lv;
      const int lrow = q0 + wv * 32 + mi * 16 + quad * 4 + r;
#pragma unroll
      for (int nt = 0; nt < 8; nt++) {
        int dd = nt * 16 + l15;
        ctx[((size_t)lrow * NB + n) * EMB + h * DH + dd] = f2bf(o_acc[mi][nt][r] * inv);
      }
    }
  }
}

extern "C" void kernel_launch(void* const* d_in, const int* in_sizes, int n_in,
                              void* d_out, int out_size, void* d_ws, size_t ws_size,
                              hipStream_t stream) {
  const float* query    = (const float*)d_in[0];
  const float* q_proj   = (const float*)d_in[1];
  const float* q_bias   = (const float*)d_in[2];
  const float* k_proj   = (const float*)d_in[3];
  const float* k_bias   = (const float*)d_in[4];
  const float* v_proj   = (const float*)d_in[5];
  const float* v_bias   = (const float*)d_in[6];
  const float* out_proj = (const float*)d_in[7];
  const float* out_bias = (const float*)d_in[8];

  u16* ws  = (u16*)d_ws;
  u16* Xbf = ws;                                  // 4096x2048 (dead after QKV gemm)
  u16* Wq  = Xbf + (size_t)MROWS * EMB;           // Wq|Wk|Wv contiguous = [6144,2048]
  u16* Wk  = Wq + (size_t)II * EMB;
  u16* Wv  = Wk + (size_t)II * EMB;
  u16* Wo  = Wv + (size_t)II * EMB;
  u16* Qw  = Wo + (size_t)EMB * II;               // [NB*NH][L][DH], Q|K|V contiguous
  u16* Kw  = Qw + (size_t)MROWS * II;
  u16* Vw  = Kw + (size_t)MROWS * II;
  u16* Cw  = Vw + (size_t)MROWS * II;             // ctx [L][NB][EMB]
  u16* Vtb = Xbf;                                 // Vt [NB*NH][DH][L] aliases Xbf

  cast_all<<<8192 + 4 * 4096, 256, 0, stream>>>(query, q_proj, k_proj, v_proj, out_proj,
                                                Xbf, Wq);

  // d^-0.5 * log2(e): base-2 softmax
  const float qscale = 0.08838834764831845f * 1.4426950408889634f;
  gemm_2p<<<768, 512, 0, stream>>>(Xbf, Wq, q_bias, k_bias, v_bias, Qw, nullptr, qscale, 0);

  transpose_v<<<dim3(L_SEQ / 64, NB * NH), 256, 0, stream>>>(Vw, Vtb);

  flash_attn<<<512, 256, 0, stream>>>(Qw, Kw, Vtb, Cw);

  gemm_2p<<<256, 512, 0, stream>>>(Cw, Wo, out_bias, nullptr, nullptr, nullptr,
                                   (float*)d_out, 1.0f, 1);
}